// Round 6
// baseline (20915.974 us; speedup 1.0000x reference)
//
#include <hip/hip_runtime.h>

#define TSTEPS 1024
#define BB 128
#define HH 512
#define NCH 80
#define NATT 10
#define NG 20
#define UU 64
#define LOG2PI 1.8378770664093453f

// ws float offsets
#define OFF_HA0 0
#define OFF_HA1 65536
#define OFF_HB  131072
#define OFF_WT  196608
#define OFF_YH  206848
#define OFF_RED 223232
#define OFF_EP  223744      // unsigned h_ep[256], b_ep[256], red_cnt
#define EP_WORDS 520

__device__ __forceinline__ float ld_scf(const float* p) {
    return __hip_atomic_load((float*)p, __ATOMIC_RELAXED, __HIP_MEMORY_SCOPE_AGENT);
}
__device__ __forceinline__ void st_scf(float* p, float v) {
    __hip_atomic_store(p, v, __ATOMIC_RELAXED, __HIP_MEMORY_SCOPE_AGENT);
}
__device__ __forceinline__ float2 ld_sc2(const float* p) {
    unsigned long long v = __hip_atomic_load((unsigned long long*)p, __ATOMIC_RELAXED, __HIP_MEMORY_SCOPE_AGENT);
    float2 f; __builtin_memcpy(&f, &v, 8); return f;
}
__device__ __forceinline__ unsigned ld_u(const unsigned* p) {
    return __hip_atomic_load((unsigned*)p, __ATOMIC_RELAXED, __HIP_MEMORY_SCOPE_AGENT);
}
__device__ __forceinline__ void st_u(unsigned* p, unsigned v) {
    __hip_atomic_store(p, v, __ATOMIC_RELAXED, __HIP_MEMORY_SCOPE_AGENT);
}

__global__ void init_sync_kernel(float* ws) {
    unsigned* s = (unsigned*)(ws + OFF_EP);
    for (int i = threadIdx.x; i < EP_WORDS; i += blockDim.x) st_u(s + i, 0u);
}

__global__ __launch_bounds__(512)
void hw_kernel(const float* __restrict__ seq_pt, const float* __restrict__ seq_mask,
               const float* __restrict__ tgt, const int* __restrict__ cidx,
               const float* __restrict__ c_mask,
               const float* __restrict__ W_ih, const float* __restrict__ b_ih,
               const float* __restrict__ W_hh, const float* __restrict__ b_hh,
               const float* __restrict__ W_att, const float* __restrict__ b_att,
               const float* __restrict__ W_mix, const float* __restrict__ b_mix,
               float* __restrict__ out, float* __restrict__ ws)
{
    const int g = blockIdx.x;
    const int tid = threadIdx.x;
    const int jblk = g >> 2;          // 0..63 (8 hidden units)
    const int bblk = g & 3;           // 0..3  (32 batches)
    const bool isAttn = (jblk < 32);
    const int pb = bblk * 32 + (isAttn ? jblk : (jblk - 32));   // phase-B batch
    // phase-A FMA role
    const int jj  = tid & 7;
    const int bg3 = (tid >> 3) & 7;
    const int ks  = tid >> 6;         // wave index = d-split (0..7)

    __shared__ float4 s_wW[8][601];              // 76.9 KB
    __shared__ __align__(16) float s_chm[9216];  // 36.9 KB: 3 chunk buffers (s_h overlay in B)
    __shared__ __align__(16) float s_part[10240];// 40 KB: partials, 512 rows x pitch 20
    __shared__ float s_pA[512], s_pB[96];
    __shared__ float s_y[124];
    __shared__ float s_wold[NCH], s_kk[16];
    __shared__ float s_phi[64];
    __shared__ int   s_ci[64];
    __shared__ float s_nA[20], s_nB[20], s_pen[1];

    // ---- persistent LDS weights ----
    for (int lin = tid; lin < 8 * 596; lin += 512) {
        int lj = lin / 596, idx = lin % 596;
        int jg = jblk * 8 + lj;
        float4 v;
        if (idx < 512) {
            v = make_float4(W_hh[(0 * HH + jg) * HH + idx], W_hh[(1 * HH + jg) * HH + idx],
                            W_hh[(2 * HH + jg) * HH + idx], W_hh[(3 * HH + jg) * HH + idx]);
        } else if (idx < 592) {
            int dd = 3 + (idx - 512);
            v = make_float4(W_ih[(0 * HH + jg) * 83 + dd], W_ih[(1 * HH + jg) * 83 + dd],
                            W_ih[(2 * HH + jg) * 83 + dd], W_ih[(3 * HH + jg) * 83 + dd]);
        } else if (idx < 595) {
            int dd = idx - 592;
            v = make_float4(W_ih[(0 * HH + jg) * 83 + dd], W_ih[(1 * HH + jg) * 83 + dd],
                            W_ih[(2 * HH + jg) * 83 + dd], W_ih[(3 * HH + jg) * 83 + dd]);
        } else {
            v = make_float4(b_ih[0 * HH + jg] + b_hh[0 * HH + jg], b_ih[1 * HH + jg] + b_hh[1 * HH + jg],
                            b_ih[2 * HH + jg] + b_hh[2 * HH + jg], b_ih[3 * HH + jg] + b_hh[3 * HH + jg]);
        }
        s_wW[lj][idx] = v;
    }
    if (tid < 16) s_kk[tid] = 0.f;
    if (tid < NCH) s_wold[tid] = 0.f;
    __syncthreads();

    unsigned* h_ep = (unsigned*)(ws + OFF_EP);
    unsigned* b_ep = h_ep + 256;
    unsigned* red_cnt = h_ep + 512;
    unsigned* h_grp = h_ep + bblk * 64;
    unsigned* b_grp = b_ep + bblk * 64;
    float* hB  = ws + OFF_HB;    // [b][d]
    float* wT  = ws + OFF_WT;    // [c][128]
    float* yh  = ws + OFF_YH;    // [b][128]
    float* red = ws + OFF_RED;

    float cell = 0.f, nll_acc = 0.f, mask_acc = 0.f;

    auto wait_slots = [&](const unsigned* base, int n, unsigned tgt_ep) {
        if (tid < n) {
            const unsigned* p = base + tid;
            while (ld_u(p) < tgt_ep) __builtin_amdgcn_s_sleep(1);
        }
        __syncthreads();
        asm volatile("" ::: "memory");
    };

    auto do_nll = [&](int tp) {   // attention WGs only; needs yh(tp), s_wold=w(tp)
        if (tid < 121) {
            const float* wr = W_mix + (size_t)tid * 592 + 512;   // cached read-only
            float acc = ld_scf(&yh[(size_t)pb * 128 + tid]) + b_mix[tid];
            #pragma unroll 8
            for (int c = 0; c < NCH; ++c) acc = fmaf(s_wold[c], wr[c], acc);
            s_y[tid] = acc;
        }
        __syncthreads();
        if (tid < 21) {
            const float* tg = tgt + ((size_t)tp * BB + pb) * 3;
            if (tid < NG) {
                int m = tid;
                float y0 = s_y[m], y1 = s_y[20 + m], y2 = s_y[40 + m];
                float y3 = s_y[60 + m], y4 = s_y[80 + m], y5 = s_y[100 + m];
                float x1 = tg[0], x2 = tg[1];
                float rho = tanhf(y5);
                float d1 = (x1 - y1) * expf(-y3);
                float d2 = (x2 - y2) * expf(-y4);
                float omr2 = 1.f - rho * rho;
                float Z = d1 * d1 + d2 * d2 - 2.f * rho * d1 * d2;
                float log_n = -Z / (2.f * omr2) - LOG2PI - y3 - y4 - 0.5f * logf(omr2);
                s_nA[m] = y0;
                s_nB[m] = y0 + log_n;
            } else {
                float yp = s_y[120];
                float pen = tg[2];
                float e = log1pf(expf(-fabsf(yp)));
                float ls_p = fminf(yp, 0.f) - e;
                float ls_n = fminf(-yp, 0.f) - e;
                s_pen[0] = -(pen * ls_p + (1.f - pen) * ls_n);
            }
        }
        __syncthreads();
        if (tid == 0) {
            float mx1 = -1e30f, mx2 = -1e30f;
            for (int m = 0; m < NG; ++m) { mx1 = fmaxf(mx1, s_nA[m]); mx2 = fmaxf(mx2, s_nB[m]); }
            float se1 = 0.f, se2 = 0.f;
            for (int m = 0; m < NG; ++m) { se1 += expf(s_nA[m] - mx1); se2 += expf(s_nB[m] - mx2); }
            float nll = (mx1 + logf(se1)) - (mx2 + logf(se2)) + s_pen[0];
            float mk = seq_mask[(size_t)tp * BB + pb];
            nll_acc += mk * nll;
            mask_acc += mk;
        }
        __syncthreads();
    };

    for (int t = 0; t < TSTEPS; ++t) {
        float* hAcur = ws + ((t & 1) ? OFF_HA1 : OFF_HA0);
        const float* hAprv = ws + ((t & 1) ? OFF_HA0 : OFF_HA1);

        // ======== phase A: 7 chunks (6x96 + 16 rows), 3 buffers, 2-deep prefetch ========
        float4 a0 = make_float4(0.f, 0.f, 0.f, 0.f);
        float4 a1 = a0, a2 = a0, a3 = a0;

        if (t > 0) {
            float2 rgA[3], rgB[3];
            auto stage_issue = [&](int r, float2* rg) {
                if (r < 6) {
                    #pragma unroll
                    for (int i = 0; i < 3; ++i) {
                        int lin = i * 512 + tid;
                        int dR = lin >> 4, c2 = lin & 15;
                        int R = r * 96 + dR;
                        const float* src = (R < 512) ? (hAprv + (size_t)R * BB)
                                                     : (wT + (size_t)(R - 512) * BB);
                        rg[i] = ld_sc2(src + bblk * 32 + c2 * 2);
                    }
                } else if (tid < 256) {
                    int dR = tid >> 4, c2 = tid & 15;
                    rg[0] = ld_sc2(wT + (size_t)(64 + dR) * BB + bblk * 32 + c2 * 2);
                }
            };
            auto stage_write = [&](int r, const float2* rg) {
                float* bufp = s_chm + (r % 3) * 3072;
                if (r < 6) {
                    #pragma unroll
                    for (int i = 0; i < 3; ++i) {
                        int lin = i * 512 + tid;
                        int dR = lin >> 4, c2 = lin & 15;
                        ((float2*)bufp)[dR * 16 + c2] = rg[i];
                    }
                } else if (tid < 256) {
                    int dR = tid >> 4, c2 = tid & 15;
                    ((float2*)bufp)[dR * 16 + c2] = rg[0];
                }
            };
            auto fma_rows = [&](const float* cb, int rb, int wb, int nd) {
                #pragma unroll 4
                for (int dl = 0; dl < nd; ++dl) {
                    float4 wv = s_wW[jj][wb + dl];
                    float4 hv = *(const float4*)&cb[(rb + dl) * 32 + bg3 * 4];
                    a0.x = fmaf(hv.x, wv.x, a0.x); a0.y = fmaf(hv.x, wv.y, a0.y);
                    a0.z = fmaf(hv.x, wv.z, a0.z); a0.w = fmaf(hv.x, wv.w, a0.w);
                    a1.x = fmaf(hv.y, wv.x, a1.x); a1.y = fmaf(hv.y, wv.y, a1.y);
                    a1.z = fmaf(hv.y, wv.z, a1.z); a1.w = fmaf(hv.y, wv.w, a1.w);
                    a2.x = fmaf(hv.z, wv.x, a2.x); a2.y = fmaf(hv.z, wv.y, a2.y);
                    a2.z = fmaf(hv.z, wv.z, a2.z); a2.w = fmaf(hv.z, wv.w, a2.w);
                    a3.x = fmaf(hv.w, wv.x, a3.x); a3.y = fmaf(hv.w, wv.y, a3.y);
                    a3.z = fmaf(hv.w, wv.z, a3.z); a3.w = fmaf(hv.w, wv.w, a3.w);
                }
            };

            wait_slots(h_grp, 64, (unsigned)t);      // h(t-1) from my bblk-group
            stage_issue(0, rgA);
            stage_issue(1, rgB);
            stage_write(0, rgA);
            __syncthreads();
            #pragma unroll 1
            for (int r = 0; r < 7; ++r) {
                if (r == 3) wait_slots(b_grp, 32, (unsigned)t);   // w(t-1) before chunk-5 issue
                if (r + 2 <= 6) stage_issue(r + 2, (r & 1) ? rgB : rgA);
                if (r + 1 <= 6) stage_write(r + 1, ((r + 1) & 1) ? rgB : rgA);
                __syncthreads();
                const float* cb = s_chm + (r % 3) * 3072;
                if (r < 6) fma_rows(cb, ks * 12, r * 96 + ks * 12, 12);
                else       fma_rows(cb, ks * 2, 576 + ks * 2, 2);
            }
            {   // partial exchange, pitch-20 (bank-spread, bandwidth-minimal)
                int R = ((ks * 8 + jj) << 3) + bg3;   // 0..511
                *(float4*)&s_part[R * 20 + 0]  = a0;
                *(float4*)&s_part[R * 20 + 4]  = a1;
                *(float4*)&s_part[R * 20 + 8]  = a2;
                *(float4*)&s_part[R * 20 + 12] = a3;
            }
        }

        // mixture B(t-1) done before hB overwrite (trailing sync also covers partials)
        wait_slots(b_grp + 32, 32, (unsigned)t);

        // pointwise LSTM: tid<256, thread = (j, b)
        if (tid < 256) {
            const int jj_o = tid >> 5, bl = tid & 31;
            const int b = bblk * 32 + bl, j = jblk * 8 + jj_o;
            float4 s = s_wW[jj_o][595];  // fused bias
            if (t > 0) {
                #pragma unroll
                for (int k2 = 0; k2 < 8; ++k2) {
                    int Rr = ((k2 * 8 + jj_o) << 3) + (bl >> 2);
                    float4 v = *(const float4*)&s_part[Rr * 20 + (bl & 3) * 4];
                    s.x += v.x; s.y += v.y; s.z += v.z; s.w += v.w;
                }
            }
            const float* ip = seq_pt + ((size_t)t * BB + b) * 3;
            float x0 = ip[0], x1 = ip[1], x2 = ip[2];
            float4 wx0 = s_wW[jj_o][592], wx1 = s_wW[jj_o][593], wx2 = s_wW[jj_o][594];
            s.x += x0 * wx0.x + x1 * wx1.x + x2 * wx2.x;
            s.y += x0 * wx0.y + x1 * wx1.y + x2 * wx2.y;
            s.z += x0 * wx0.z + x1 * wx1.z + x2 * wx2.z;
            s.w += x0 * wx0.w + x1 * wx1.w + x2 * wx2.w;
            float ig = 1.f / (1.f + expf(-s.x));
            float fg = 1.f / (1.f + expf(-s.y));
            float gg = tanhf(s.z);
            float og = 1.f / (1.f + expf(-s.w));
            cell = fg * cell + ig * gg;
            float hval = og * tanhf(cell);
            st_scf(hAcur + (size_t)j * BB + b, hval);
            st_scf(hB + (size_t)b * HH + j, hval);
        }
        asm volatile("s_waitcnt vmcnt(0)" ::: "memory");
        __syncthreads();
        if (tid == 0) st_u(&h_ep[bblk * 64 + jblk], (unsigned)(t + 1));   // h(t) published

        // NLL(t-1): yh(t-1) guaranteed by the b_grp+32 wait above
        if (isAttn && t > 0) do_nll(t - 1);

        // ======== phase B ========
        wait_slots(h_grp, 64, (unsigned)(t + 1));   // full h(t) for my group's batches
        {
            float* s_h = s_chm;
            if (tid < 256) ((float2*)s_h)[tid] = ld_sc2(hB + (size_t)pb * HH + tid * 2);
            __syncthreads();
            float mk = seq_mask[(size_t)t * BB + pb];
            if (isAttn) {
                int m = tid & 31, seg = tid >> 5;    // 16 segments x 32 d
                if (m < 30) {
                    const float* wa = W_att + (size_t)m * HH + seg * 32;
                    const float* hb = s_h + seg * 32;
                    float acc = 0.f;
                    #pragma unroll 8
                    for (int d = 0; d < 32; ++d) acc = fmaf(hb[d], wa[d], acc);
                    s_pA[seg * 32 + m] = acc;
                }
                __syncthreads();
                if (tid < 30) {
                    float v = b_att[tid];
                    #pragma unroll
                    for (int o = 0; o < 16; ++o) v += s_pA[o * 32 + tid];
                    s_pB[tid] = v;
                }
                __syncthreads();
                if (tid < NATT) {
                    float ah = s_pB[tid], bh = s_pB[10 + tid], kh = s_pB[20 + tid];
                    float kprev = s_kk[tid];
                    float kn = kprev + expf(kh);
                    s_pB[32 + tid] = expf(ah);
                    s_pB[48 + tid] = expf(bh);
                    s_pB[64 + tid] = kn;
                    s_kk[tid] = mk * kn + (1.f - mk) * kprev;
                }
                __syncthreads();
                if (tid < UU) {
                    float uu = (float)tid;
                    float phi = 0.f;
                    #pragma unroll
                    for (int a = 0; a < NATT; ++a) {
                        float diff = s_pB[64 + a] - uu;
                        phi = fmaf(s_pB[32 + a], expf(-s_pB[48 + a] * diff * diff), phi);
                    }
                    s_phi[tid] = phi * c_mask[(size_t)tid * BB + pb];
                    s_ci[tid] = cidx[(size_t)tid * BB + pb];
                }
                __syncthreads();
                if (tid < NCH) {
                    float wn = 0.f;
                    for (int u = 0; u < UU; ++u)
                        wn += (s_ci[u] == tid) ? s_phi[u] : 0.f;
                    float wold = (t > 0) ? s_wold[tid] : 0.f;
                    float wnew = mk * wn + (1.f - mk) * wold;
                    s_wold[tid] = wnew;
                    st_scf(wT + (size_t)tid * BB + pb, wnew);
                }
            } else {
                if (tid < 484) {                     // 121 outputs x 4 quarter-dots of 128 d
                    int m = tid >> 2, qf = tid & 3;
                    const float* wm = W_mix + (size_t)m * 592 + qf * 128;
                    const float* hb = s_h + qf * 128;
                    float acc = 0.f;
                    #pragma unroll 8
                    for (int d = 0; d < 128; ++d) acc = fmaf(hb[d], wm[d], acc);
                    s_pA[tid] = acc;
                }
                __syncthreads();
                if (tid < 121)
                    st_scf(yh + (size_t)pb * 128 + tid,
                           s_pA[4 * tid] + s_pA[4 * tid + 1] + s_pA[4 * tid + 2] + s_pA[4 * tid + 3]);
            }
        }
        asm volatile("s_waitcnt vmcnt(0)" ::: "memory");
        __syncthreads();
        if (tid == 0) st_u(&b_ep[bblk * 64 + jblk], (unsigned)(t + 1));   // w(t)/yh(t) published
    }

    // ======== epilogue: NLL(1023) + reduction ========
    if (isAttn) {
        wait_slots(b_grp + 32, 32, (unsigned)TSTEPS);   // yh(1023) ready
        do_nll(TSTEPS - 1);
        if (tid == 0) {
            st_scf(red + pb, nll_acc);
            st_scf(red + BB + pb, mask_acc);
        }
        asm volatile("s_waitcnt vmcnt(0)" ::: "memory");
        __syncthreads();
        if (tid == 0)
            __hip_atomic_fetch_add(red_cnt, 1u, __ATOMIC_RELAXED, __HIP_MEMORY_SCOPE_AGENT);
    }
    if (g == 0) {
        if (tid == 0) {
            while (ld_u(red_cnt) < 128u) __builtin_amdgcn_s_sleep(2);
            asm volatile("" ::: "memory");
            float sn = 0.f, sm = 0.f;
            for (int i = 0; i < BB; ++i) { sn += ld_scf(red + i); sm += ld_scf(red + BB + i); }
            out[0] = sn / sm;
        }
    }
}

extern "C" void kernel_launch(void* const* d_in, const int* in_sizes, int n_in,
                              void* d_out, int out_size, void* d_ws, size_t ws_size,
                              hipStream_t stream) {
    (void)in_sizes; (void)n_in; (void)out_size; (void)ws_size;
    const float* seq_pt   = (const float*)d_in[0];
    const float* seq_mask = (const float*)d_in[1];
    const float* tgt      = (const float*)d_in[2];
    const int*   cidx     = (const int*)d_in[3];
    const float* c_mask   = (const float*)d_in[4];
    const float* W_ih     = (const float*)d_in[5];
    const float* b_ih     = (const float*)d_in[6];
    const float* W_hh     = (const float*)d_in[7];
    const float* b_hh     = (const float*)d_in[8];
    const float* W_att    = (const float*)d_in[9];
    const float* b_att    = (const float*)d_in[10];
    const float* W_mix    = (const float*)d_in[11];
    const float* b_mix    = (const float*)d_in[12];
    float* out = (float*)d_out;
    float* ws  = (float*)d_ws;

    hipLaunchKernelGGL(init_sync_kernel, dim3(1), dim3(256), 0, stream, ws);
    hipLaunchKernelGGL(hw_kernel, dim3(256), dim3(512), 0, stream,
                       seq_pt, seq_mask, tgt, cidx, c_mask,
                       W_ih, b_ih, W_hh, b_hh, W_att, b_att,
                       W_mix, b_mix, out, ws);
}